// Round 14
// baseline (124.821 us; speedup 1.0000x reference)
//
#include <hip/hip_runtime.h>
#include <math.h>

// AFM: B=4096, F=50, D=16, A=32, P=1225 pairs.
// out[b] = sum_p softmax_p( relu(inter_p @ W) . h ) * (inter_p . p_vec)
//
// Round 14: DIAGNOSTIC A/B vs R8. Exact R8 launch config (128 blocks x 256
// thr, BPB=32, 1 wave/SIMD, LDS 81920 B) with R12's improved core (packed
// f16 epilogue, fdot2 g, raw exp2, dual streams, quad-table b128).
// Purpose: afm_kernel visible above the 41us harness fills -> read
// VALUBusy/MfmaUtil; per-tile issued cyc vs R8's 332 decides whether the
// packed diet reduced emitted instructions (then: pipeline next) or not
// (then: revert to R12, practical ceiling).
//  - mfma_f32_32x32x16_f16 (K=16), layouts validated R4-R13.
//  - No-max softmax in log2 domain; g per-K-half; out = 2*num/den.

#define FF 50
#define DD 16
#define AA 32
#define NP 1225
#define NT 39
#define NQ4 10             // quad-groups of tiles (40 slots)
#define ERS 24             // halves per e-row (48 B)
#define EBS (FF * ERS)     // 1200 halves per batch element
#define BPB 32             // batches per block (8 per wave, sequential)
#define NTHR 256

typedef _Float16 half8 __attribute__((ext_vector_type(8)));
typedef _Float16 half4 __attribute__((ext_vector_type(4)));
typedef _Float16 half2v __attribute__((ext_vector_type(2)));
typedef __fp16   fh2    __attribute__((ext_vector_type(2)));
typedef float    floatx16 __attribute__((ext_vector_type(16)));

__global__ __launch_bounds__(NTHR) void afm_kernel(
    const float* __restrict__ feat,   // [B, 50, 16]
    const float* __restrict__ W,      // [16, 32]
    const float* __restrict__ h,      // [32]
    const float* __restrict__ pvec,   // [16]
    float* __restrict__ out,          // [B]
    int Btot)
{
  __shared__ __align__(16) _Float16 eh[BPB * EBS];      // 76800 B
  __shared__ __align__(16) unsigned int tbl[NQ4 * 128]; // 5120 B, quad layout

  const int tid    = threadIdx.x;
  const int lane   = tid & 63;
  const int wave   = tid >> 6;       // 0..3
  const int halfid = lane >> 5;
  const int n      = lane & 31;
  const int b0     = blockIdx.x * BPB;

  // ---- stage 32 batch elements -> f16 LDS ----
  for (int s = tid; s < BPB * 200; s += NTHR) {
    int bl  = s / 200;
    int rem = s - bl * 200;
    int bb  = b0 + bl;
    if (bb < Btot) {
      float4 v4 = ((const float4*)feat)[(size_t)bb * 200 + rem];
      half4 hv;
      hv[0] = (_Float16)v4.x; hv[1] = (_Float16)v4.y;
      hv[2] = (_Float16)v4.z; hv[3] = (_Float16)v4.w;
      int row = rem >> 2, q = rem & 3;
      *(half4*)(&eh[bl * EBS + row * ERS + q * 4]) = hv;
    }
  }

  // ---- pair table, quad layout: tbl[q4*128 + n*4 + u] = ent(t=4*q4+u, n) ----
  for (int q = tid; q < NQ4 * 128; q += NTHR) {
    int q4  = q >> 7;
    int rem = q & 127;
    int nn  = rem >> 2;
    int u   = rem & 3;
    int p   = (4 * q4 + u) * 32 + nn;
    unsigned ent = 0;
    if (p < NP) {
      int rad = 9801 - 8 * p;
      int i = (int)((99.0f - sqrtf((float)rad)) * 0.5f);
      if (i < 0) i = 0; if (i > 48) i = 48;
      int off = (i * (99 - i)) >> 1;
      if (off > p) { --i; off = (i * (99 - i)) >> 1; }
      else {
        int off1 = ((i + 1) * (98 - i)) >> 1;
        if (off1 <= p) { ++i; off = off1; }
      }
      int j = p - off + i + 1;
      ent = ((unsigned)(i * 48) << 16) | (unsigned)(j * 48);
    }
    tbl[q] = ent;
  }

  // ---- loop-invariant fragments ----
  const float LOG2E = 1.4426950408889634f;
  half8 A0;
  #pragma unroll
  for (int jj = 0; jj < 8; ++jj)
    A0[jj] = (_Float16)W[(halfid * 8 + jj) * AA + n];
  fh2 h2[8];
  #pragma unroll
  for (int q = 0; q < 8; ++q) {
    h2[q][0] = (__fp16)(h[((2*q) & 3) + 8 * ((2*q) >> 2) + 4 * halfid] * LOG2E);
    h2[q][1] = (__fp16)(h[((2*q+1) & 3) + 8 * ((2*q+1) >> 2) + 4 * halfid] * LOG2E);
  }
  fh2 pv2[4];
  #pragma unroll
  for (int q = 0; q < 4; ++q) {
    pv2[q][0] = (__fp16)pvec[halfid * 8 + 2 * q];
    pv2[q][1] = (__fp16)pvec[halfid * 8 + 2 * q + 1];
  }
  const floatx16 ZACC = (floatx16)0.0f;
  const fh2 zz = {(__fp16)0.f, (__fp16)0.f};

  __syncthreads();

  const unsigned int* tq = tbl + n * 4;       // this lane's quad column

#if __has_builtin(__builtin_amdgcn_exp2f)
  #define EXP2(x) __builtin_amdgcn_exp2f(x)
#else
  #define EXP2(x) exp2f(x)
#endif

  // ---- each wave owns 8 batches sequentially (R8 mapping) ----
  for (int grp = 0; grp < 8; ++grp) {
    const int b = b0 + wave * 8 + grp;
    const char* eb = (const char*)(eh + (wave * 8 + grp) * EBS) + halfid * 16;

    auto core = [&](unsigned ij, float& vout, float& gout) {
      half8 Bi = *(const half8*)(eb + (ij >> 16));
      half8 Bj = *(const half8*)(eb + (ij & 0xffffu));
      half8 Bv = Bi * Bj;                     // 4x v_pk_mul_f16
      floatx16 z = __builtin_amdgcn_mfma_f32_32x32x16_f16(A0, Bv, ZACC, 0, 0, 0);
      float vL = 0.f, vH = 0.f;
      #pragma unroll
      for (int q = 0; q < 4; ++q) {
        fh2 zp = __builtin_amdgcn_cvt_pkrtz(z[2*q], z[2*q+1]);
        fh2 zr = __builtin_elementwise_max(zp, zz);     // v_pk_max_f16
        vL = __builtin_amdgcn_fdot2(zr, h2[q], vL, false);
      }
      #pragma unroll
      for (int q = 4; q < 8; ++q) {
        fh2 zp = __builtin_amdgcn_cvt_pkrtz(z[2*q], z[2*q+1]);
        fh2 zr = __builtin_elementwise_max(zp, zz);
        vH = __builtin_amdgcn_fdot2(zr, h2[q], vH, false);
      }
      float v = vL + vH;
      vout = v + __shfl_xor(v, 32, 64);       // full score (log2 domain)
      fh2 q0 = __builtin_bit_cast(fh2, (half2v)__builtin_shufflevector(Bv, Bv, 0, 1));
      fh2 q1 = __builtin_bit_cast(fh2, (half2v)__builtin_shufflevector(Bv, Bv, 2, 3));
      fh2 q2 = __builtin_bit_cast(fh2, (half2v)__builtin_shufflevector(Bv, Bv, 4, 5));
      fh2 q3 = __builtin_bit_cast(fh2, (half2v)__builtin_shufflevector(Bv, Bv, 6, 7));
      gout = __builtin_amdgcn_fdot2(q1, pv2[1],
             __builtin_amdgcn_fdot2(q0, pv2[0], 0.f, false), false)
           + __builtin_amdgcn_fdot2(q3, pv2[3],
             __builtin_amdgcn_fdot2(q2, pv2[2], 0.f, false), false);
    };

    // dual independent accumulation streams (R12)
    float den0 = 0.f, num0 = 0.f, den1 = 0.f, num1 = 0.f;
    for (int q4 = 0; q4 < 9; ++q4) {          // tiles 0..35, all valid
      uint4 e4 = *(const uint4*)(tq + (q4 << 7));
      float v0, g0, v1, g1, v2, g2, v3, g3;
      core(e4.x, v0, g0);
      core(e4.y, v1, g1);
      core(e4.z, v2, g2);
      core(e4.w, v3, g3);
      float ex0 = EXP2(v0), ex1 = EXP2(v1), ex2 = EXP2(v2), ex3 = EXP2(v3);
      den0 += ex0; num0 = fmaf(ex0, g0, num0);
      den1 += ex1; num1 = fmaf(ex1, g1, num1);
      den0 += ex2; num0 = fmaf(ex2, g2, num0);
      den1 += ex3; num1 = fmaf(ex3, g3, num1);
    }
    {                                         // quad 9: tiles 36,37,38(part)
      uint4 e4 = *(const uint4*)(tq + (9 << 7));
      float v0, g0, v1, g1, v2, g2;
      core(e4.x, v0, g0);
      core(e4.y, v1, g1);
      core(e4.z, v2, g2);
      if (n >= 9) v2 = -3.0e38f;              // tile 38: valid n < 9
      float ex0 = EXP2(v0), ex1 = EXP2(v1), ex2 = EXP2(v2);
      den0 += ex0; num0 = fmaf(ex0, g0, num0);
      den1 += ex1; num1 = fmaf(ex1, g1, num1);
      den0 += ex2; num0 = fmaf(ex2, g2, num0);
    }
    float den = den0 + den1, num = num0 + num1;

    #pragma unroll
    for (int mask = 32; mask >= 1; mask >>= 1) {
      den += __shfl_xor(den, mask, 64);
      num += __shfl_xor(num, mask, 64);
    }
    if (lane == 0 && b < Btot) out[b] = (2.0f * num) / den;
  }
}

extern "C" void kernel_launch(void* const* d_in, const int* in_sizes, int n_in,
                              void* d_out, int out_size, void* d_ws, size_t ws_size,
                              hipStream_t stream) {
  const float* feat = (const float*)d_in[0];
  const float* W    = (const float*)d_in[1];
  const float* h    = (const float*)d_in[2];
  const float* pvec = (const float*)d_in[3];
  float* out = (float*)d_out;
  const int B = in_sizes[0] / (FF * DD);   // 4096
  afm_kernel<<<(B + BPB - 1) / BPB, NTHR, 0, stream>>>(feat, W, h, pvec, out, B);
}

// Round 16
// 80.506 us; speedup vs baseline: 1.5504x; 1.5504x over previous
//
#include <hip/hip_runtime.h>
#include <math.h>

// AFM: B=4096, F=50, D=16, A=32, P=1225 pairs.
// out[b] = sum_p softmax_p( relu(inter_p @ W) . h ) * (inter_p . p_vec)
//
// Round 16: R15 phase-batched quad pipeline, minus the software table
// prefetch (sole untested pattern in R15's core-dumped build; table loads
// here are byte-identical to R13's proven pattern). R12 config: 512 thr,
// BPB=8, grid 512 = 2 blocks/CU, 4 waves/SIMD.
// Per 4-tile quad: (A) 8x ds_read_b128 + pk_mul + g-dots, (B) 4 MFMAs,
// (C) 4 packed relu.h epilogues, (D) 4 back-to-back shfls (one lgkm drain
// covers all), (E) 4 exp2 + dual-stream accumulate.
//  - mfma_f32_32x32x16_f16 (K=16), layouts validated R4-R14:
//    A[m=lane&31][k=(lane>>5)*8+jj], B[k][n=lane&31],
//    C/D row a=(reg&3)+8*(reg>>2)+4*(lane>>5), col n=lane&31.
//  - No-max softmax in log2 domain (validated R7-R14); g per-K-half,
//    merged in the pure-add butterfly; out = 2*num/den.

#define FF 50
#define DD 16
#define AA 32
#define NP 1225
#define NT 39
#define NQ4 10             // quad-groups of tiles (40 slots)
#define ERS 24             // halves per e-row (48 B)
#define EBS (FF * ERS)     // 1200 halves per batch element
#define BPB 8              // batches per block = waves per block
#define NTHR 512

typedef _Float16 half8 __attribute__((ext_vector_type(8)));
typedef _Float16 half4 __attribute__((ext_vector_type(4)));
typedef _Float16 half2v __attribute__((ext_vector_type(2)));
typedef __fp16   fh2    __attribute__((ext_vector_type(2)));
typedef float    floatx16 __attribute__((ext_vector_type(16)));

__global__ __launch_bounds__(NTHR, 4) void afm_kernel(
    const float* __restrict__ feat,   // [B, 50, 16]
    const float* __restrict__ W,      // [16, 32]
    const float* __restrict__ h,      // [32]
    const float* __restrict__ pvec,   // [16]
    float* __restrict__ out,          // [B]
    int Btot)
{
  __shared__ __align__(16) _Float16 eh[BPB * EBS];      // 19200 B
  __shared__ __align__(16) unsigned int tbl[NQ4 * 128]; // 5120 B, quad layout

  const int tid    = threadIdx.x;
  const int lane   = tid & 63;
  const int wave   = tid >> 6;       // 0..7, owns batch b0+wave
  const int halfid = lane >> 5;
  const int n      = lane & 31;
  const int b0     = blockIdx.x * BPB;

  // ---- stage 8 batch elements -> f16 LDS ----
  for (int s = tid; s < BPB * 200; s += NTHR) {
    int bl  = s / 200;
    int rem = s - bl * 200;
    int bb  = b0 + bl;
    if (bb < Btot) {
      float4 v4 = ((const float4*)feat)[(size_t)bb * 200 + rem];
      half4 hv;
      hv[0] = (_Float16)v4.x; hv[1] = (_Float16)v4.y;
      hv[2] = (_Float16)v4.z; hv[3] = (_Float16)v4.w;
      int row = rem >> 2, q = rem & 3;
      *(half4*)(&eh[bl * EBS + row * ERS + q * 4]) = hv;
    }
  }

  // ---- pair table, quad layout: tbl[q4*128 + n*4 + u] = ent(t=4*q4+u, n)
  //      ent = (i*48)<<16 | (j*48); 0 for pad slots ----
  for (int q = tid; q < NQ4 * 128; q += NTHR) {
    int q4  = q >> 7;
    int rem = q & 127;
    int nn  = rem >> 2;
    int u   = rem & 3;
    int p   = (4 * q4 + u) * 32 + nn;
    unsigned ent = 0;
    if (p < NP) {
      int rad = 9801 - 8 * p;
      int i = (int)((99.0f - sqrtf((float)rad)) * 0.5f);
      if (i < 0) i = 0; if (i > 48) i = 48;
      int off = (i * (99 - i)) >> 1;
      if (off > p) { --i; off = (i * (99 - i)) >> 1; }
      else {
        int off1 = ((i + 1) * (98 - i)) >> 1;
        if (off1 <= p) { ++i; off = off1; }
      }
      int j = p - off + i + 1;
      ent = ((unsigned)(i * 48) << 16) | (unsigned)(j * 48);
    }
    tbl[q] = ent;
  }

  // ---- loop-invariant fragments ----
  const float LOG2E = 1.4426950408889634f;
  half8 A0;
  #pragma unroll
  for (int jj = 0; jj < 8; ++jj)
    A0[jj] = (_Float16)W[(halfid * 8 + jj) * AA + n];
  fh2 h2[8];
  #pragma unroll
  for (int q = 0; q < 8; ++q) {
    h2[q][0] = (__fp16)(h[((2*q) & 3) + 8 * ((2*q) >> 2) + 4 * halfid] * LOG2E);
    h2[q][1] = (__fp16)(h[((2*q+1) & 3) + 8 * ((2*q+1) >> 2) + 4 * halfid] * LOG2E);
  }
  fh2 pv2[4];
  #pragma unroll
  for (int q = 0; q < 4; ++q) {
    pv2[q][0] = (__fp16)pvec[halfid * 8 + 2 * q];
    pv2[q][1] = (__fp16)pvec[halfid * 8 + 2 * q + 1];
  }
  const floatx16 ZACC = (floatx16)0.0f;
  const fh2 zz = {(__fp16)0.f, (__fp16)0.f};

  __syncthreads();

  // ---- main loop: this wave owns batch b0+wave ----
  const char* eb = (const char*)(eh + wave * EBS) + halfid * 16;
  const unsigned int* tq = tbl + n * 4;       // this lane's quad column

#if __has_builtin(__builtin_amdgcn_exp2f)
  #define EXP2(x) __builtin_amdgcn_exp2f(x)
#else
  #define EXP2(x) exp2f(x)
#endif

  // phase A helper: B-fragment + g partial (no z dependence)
  auto mkB = [&](unsigned ij, float& gout) -> half8 {
    half8 Bi = *(const half8*)(eb + (ij >> 16));
    half8 Bj = *(const half8*)(eb + (ij & 0xffffu));
    half8 Bv = Bi * Bj;                       // 4x v_pk_mul_f16
#if __has_builtin(__builtin_amdgcn_fdot2)
    fh2 q0 = __builtin_bit_cast(fh2, (half2v)__builtin_shufflevector(Bv, Bv, 0, 1));
    fh2 q1 = __builtin_bit_cast(fh2, (half2v)__builtin_shufflevector(Bv, Bv, 2, 3));
    fh2 q2 = __builtin_bit_cast(fh2, (half2v)__builtin_shufflevector(Bv, Bv, 4, 5));
    fh2 q3 = __builtin_bit_cast(fh2, (half2v)__builtin_shufflevector(Bv, Bv, 6, 7));
    gout = __builtin_amdgcn_fdot2(q1, pv2[1],
           __builtin_amdgcn_fdot2(q0, pv2[0], 0.f, false), false)
         + __builtin_amdgcn_fdot2(q3, pv2[3],
           __builtin_amdgcn_fdot2(q2, pv2[2], 0.f, false), false);
#else
    float gp = 0.f;
    #pragma unroll
    for (int k = 0; k < 8; ++k)
      gp = fmaf((float)Bv[k], (float)((const __fp16*)pv2)[k], gp);
    gout = gp;
#endif
    return Bv;
  };
  // phase C helper: packed relu.h epilogue -> half-partial score
  auto epi = [&](const floatx16& z) -> float {
    float vL = 0.f, vH = 0.f;
    #pragma unroll
    for (int q = 0; q < 4; ++q) {
      fh2 zp = __builtin_amdgcn_cvt_pkrtz(z[2*q], z[2*q+1]);
      fh2 zr = __builtin_elementwise_max(zp, zz);       // v_pk_max_f16
      vL = __builtin_amdgcn_fdot2(zr, h2[q], vL, false);
    }
    #pragma unroll
    for (int q = 4; q < 8; ++q) {
      fh2 zp = __builtin_amdgcn_cvt_pkrtz(z[2*q], z[2*q+1]);
      fh2 zr = __builtin_elementwise_max(zp, zz);
      vH = __builtin_amdgcn_fdot2(zr, h2[q], vH, false);
    }
    return vL + vH;
  };

  float den0 = 0.f, num0 = 0.f, den1 = 0.f, num1 = 0.f;

  for (int q4 = 0; q4 < 9; ++q4) {            // tiles 0..35, all valid
    uint4 cur = *(const uint4*)(tq + (q4 << 7));   // R13's proven load
    // A: fragments + g (8x ds_read_b128 batched up front)
    float g0, g1, g2, g3;
    half8 B0 = mkB(cur.x, g0);
    half8 B1 = mkB(cur.y, g1);
    half8 B2 = mkB(cur.z, g2);
    half8 B3 = mkB(cur.w, g3);
    // B: 4 MFMAs
    floatx16 z0 = __builtin_amdgcn_mfma_f32_32x32x16_f16(A0, B0, ZACC, 0, 0, 0);
    floatx16 z1 = __builtin_amdgcn_mfma_f32_32x32x16_f16(A0, B1, ZACC, 0, 0, 0);
    floatx16 z2 = __builtin_amdgcn_mfma_f32_32x32x16_f16(A0, B2, ZACC, 0, 0, 0);
    floatx16 z3 = __builtin_amdgcn_mfma_f32_32x32x16_f16(A0, B3, ZACC, 0, 0, 0);
    // C: epilogues (half-partials)
    float p0 = epi(z0), p1 = epi(z1), p2 = epi(z2), p3 = epi(z3);
    // D: back-to-back half-combines (one lgkm drain covers all four)
    float s0 = __shfl_xor(p0, 32, 64);
    float s1 = __shfl_xor(p1, 32, 64);
    float s2 = __shfl_xor(p2, 32, 64);
    float s3 = __shfl_xor(p3, 32, 64);
    // E: exp2 + dual-stream accumulate
    float ex0 = EXP2(p0 + s0), ex1 = EXP2(p1 + s1);
    float ex2 = EXP2(p2 + s2), ex3 = EXP2(p3 + s3);
    den0 += ex0; num0 = fmaf(ex0, g0, num0);
    den1 += ex1; num1 = fmaf(ex1, g1, num1);
    den0 += ex2; num0 = fmaf(ex2, g2, num0);
    den1 += ex3; num1 = fmaf(ex3, g3, num1);
  }
  {                                           // quad 9: tiles 36,37,38(partial)
    uint4 cur = *(const uint4*)(tq + (9 << 7));
    float g0, g1, g2;
    half8 B0 = mkB(cur.x, g0);
    half8 B1 = mkB(cur.y, g1);
    half8 B2 = mkB(cur.z, g2);
    floatx16 z0 = __builtin_amdgcn_mfma_f32_32x32x16_f16(A0, B0, ZACC, 0, 0, 0);
    floatx16 z1 = __builtin_amdgcn_mfma_f32_32x32x16_f16(A0, B1, ZACC, 0, 0, 0);
    floatx16 z2 = __builtin_amdgcn_mfma_f32_32x32x16_f16(A0, B2, ZACC, 0, 0, 0);
    float p0 = epi(z0), p1 = epi(z1), p2 = epi(z2);
    float s0 = __shfl_xor(p0, 32, 64);
    float s1 = __shfl_xor(p1, 32, 64);
    float s2 = __shfl_xor(p2, 32, 64);
    float v2 = (n < 9) ? (p2 + s2) : -3.0e38f;    // tile 38: valid n < 9
    float ex0 = EXP2(p0 + s0), ex1 = EXP2(p1 + s1), ex2 = EXP2(v2);
    den0 += ex0; num0 = fmaf(ex0, g0, num0);
    den1 += ex1; num1 = fmaf(ex1, g1, num1);
    den0 += ex2; num0 = fmaf(ex2, g2, num0);
  }
  float den = den0 + den1, num = num0 + num1;

  // ---- butterfly: pure adds (mask-32 merges g-halves; den double-counts) ----
  #pragma unroll
  for (int mask = 32; mask >= 1; mask >>= 1) {
    den += __shfl_xor(den, mask, 64);
    num += __shfl_xor(num, mask, 64);
  }
  const int b = b0 + wave;
  if (lane == 0 && b < Btot) out[b] = (2.0f * num) / den;
}

extern "C" void kernel_launch(void* const* d_in, const int* in_sizes, int n_in,
                              void* d_out, int out_size, void* d_ws, size_t ws_size,
                              hipStream_t stream) {
  const float* feat = (const float*)d_in[0];
  const float* W    = (const float*)d_in[1];
  const float* h    = (const float*)d_in[2];
  const float* pvec = (const float*)d_in[3];
  float* out = (float*)d_out;
  const int B = in_sizes[0] / (FF * DD);   // 4096
  afm_kernel<<<(B + BPB - 1) / BPB, NTHR, 0, stream>>>(feat, W, h, pvec, out, B);
}